// Round 4
// baseline (534.823 us; speedup 1.0000x reference)
//
#include <hip/hip_runtime.h>

// LocallyConnected3DFlipout:
//   out[b,p,f] = sum_k patch[b,p,k]*loc[p,k,f]
//              + sign_out[b,p,f]*sum_k (x*sign_in)patch[b,p,k]*(softplus(rho)*eps)[p,k,f]
//              + bias[f]
// patch k = c*27 + (kd*9+kh*3+kw)  (channel slowest, spatial row-major fastest).
//
// R11: software-pipelined persistent blocks. R7/R9/R10 post-mortem: three
// different structures all land 85-93us; per-wave lifetime ~14us vs ~4.5us of
// issue; HBM pinned at 1.26 TB/s (16%). Shared flaw: stage->barrier->compute
// phase convoy — HBM only flows during stage (~20% duty), VALU only during
// compute. Fix: overlap them.
//  - Keep R10's verified 1-batch/thread compute body (8 accumulators).
//  - PPB=8, 256 threads (8 pos x 32 batches): packed double-buffer is only
//    2 x 13.9 KB = 27.9 KB LDS -> LDS never binds occupancy.
//  - Persistent grid 1024 = 4 blocks/CU, ALL resident (no 2nd generation).
//    Per-XCD 343 tiles over 128 slots via Bresenham (n=2 or 3, contiguous,
//    evenly interleaved so each CU gets a 2/3 mix -> balanced).
//  - Per tile: next tile's 9-12 float4 loads issued in 3 groups interleaved
//    between 9-tap compute chunks (<=24 VGPR in flight — NOT R5's bulk
//    prefetch that spilled), softplus+pack+ds_write one chunk later so ~350cy
//    of FMA hides L3/HBM latency. One barrier per tile.
//  - No launch_bounds min-waves (R8: forcing the allocator = 1.46GB spill).
// LDS read pattern: lanes with equal pl broadcast (free); 8 distinct pl ->
// 8 distinct 4-bank groups (stride 436 dw == 20 mod 32) -> conflict-free.

constexpr int Bn   = 32;
constexpr int Dn   = 30;
constexpr int Cn   = 4;
constexpr int ODn  = 28;
constexpr int Pn   = ODn * ODn * ODn;   // 21952
constexpr int Tt   = 27;
constexpr int Kn   = Tt * Cn;           // 108
constexpr int PPB  = 8;                 // positions per tile
constexpr int NT   = Pn / PPB;          // 2744 tiles = 8 * 343
constexpr int THREADS = 256;            // 8 pos x 32 batches, 1 batch/thread
constexpr int WSTRIDE = Kn + 1;         // 109
constexpr int UNITS = PPB * Kn;         // 864 float4 units per array per tile
constexpr int TPX  = NT / 8;            // 343 tiles per XCD (exact)
constexpr int SLOTS = 128;              // slots per XCD
constexpr int GRID = SLOTS * 8;         // 1024 = 4 blocks/CU, all resident

__device__ __forceinline__ unsigned bf16rne(float f) {
    unsigned u = __float_as_uint(f);
    return (u + 0x7fffu + ((u >> 16) & 1u)) >> 16;
}
__device__ __forceinline__ float bflo(unsigned u) { return __uint_as_float(u << 16); }
__device__ __forceinline__ float bfhi(unsigned u) { return __uint_as_float(u & 0xffff0000u); }

__device__ __forceinline__ uint4 pack_w(const float4 L, const float4 R, const float4 E) {
    float nx = (R.x > 15.f ? R.x : __logf(1.f + __expf(R.x))) * E.x;
    float ny = (R.y > 15.f ? R.y : __logf(1.f + __expf(R.y))) * E.y;
    float nz = (R.z > 15.f ? R.z : __logf(1.f + __expf(R.z))) * E.z;
    float nw = (R.w > 15.f ? R.w : __logf(1.f + __expf(R.w))) * E.w;
    uint4 pk;
    pk.x = bf16rne(L.x) | (bf16rne(L.y) << 16);
    pk.y = bf16rne(L.z) | (bf16rne(L.w) << 16);
    pk.z = bf16rne(nx)  | (bf16rne(ny) << 16);
    pk.w = bf16rne(nz)  | (bf16rne(nw) << 16);
    return pk;
}

__global__ __launch_bounds__(THREADS) void lc3d_flipout_kernel(
    const float* __restrict__ x,        // [B,30,30,30,4]
    const float* __restrict__ loc,      // [P,108,4]
    const float* __restrict__ rho,      // [P,108,4]
    const float* __restrict__ bias,     // [4]
    const float* __restrict__ eps,      // [P,108,4]
    const float* __restrict__ sgn_in,   // [B,30,30,30,4]
    const float* __restrict__ sgn_out,  // [B,P,4]
    float* __restrict__ out)            // [B,P,4]
{
    __shared__ uint4 wsh[2][PPB * WSTRIDE];   // 2 x 13,952 B = 27,904 B

    const int tid = threadIdx.x;

    // ---- XCD-contiguous persistent assignment, Bresenham 343 over 128 ----
    const int xcd  = blockIdx.x & 7;
    const int slot = blockIdx.x >> 3;
    const int tA = (slot * TPX) >> 7;          // slot*343/128
    const int tB = ((slot + 1) * TPX) >> 7;
    const int T0 = xcd * TPX + tA;
    const int n  = tB - tA;                    // 2 or 3, evenly interleaved

    const float4* loc4 = (const float4*)loc;
    const float4* rho4 = (const float4*)rho;
    const float4* eps4 = (const float4*)eps;
    const float4* x4   = (const float4*)x;
    const float4* s4   = (const float4*)sgn_in;
    const float4  bi   = *(const float4*)bias;

    const int pl = tid & 7;
    const int b  = tid >> 3;                   // 0..31
    const bool tail = (tid < UNITS - 3 * THREADS);   // tid < 96: 4th stage unit

    // Stage-unit global indices and (padded) LDS offsets, fixed per thread.
    const int g0 = tid, g1 = tid + 256, g2 = tid + 512, g3 = tid + 768;
    const int o0 = (g0 / Kn) * WSTRIDE + (g0 % Kn);
    const int o1 = (g1 / Kn) * WSTRIDE + (g1 % Kn);
    const int o2 = (g2 / Kn) * WSTRIDE + (g2 % Kn);
    const int o3 = (g3 / Kn) * WSTRIDE + (g3 % Kn);

    // ---- Prologue: stage tile T0 into buffer 0 (loads hoisted) ----
    {
        const size_t base = (size_t)T0 * UNITS;
        const float4 L0 = loc4[base + g0], R0 = rho4[base + g0], E0 = eps4[base + g0];
        const float4 L1 = loc4[base + g1], R1 = rho4[base + g1], E1 = eps4[base + g1];
        const float4 L2 = loc4[base + g2], R2 = rho4[base + g2], E2 = eps4[base + g2];
        wsh[0][o0] = pack_w(L0, R0, E0);
        wsh[0][o1] = pack_w(L1, R1, E1);
        wsh[0][o2] = pack_w(L2, R2, E2);
        if (tail)
            wsh[0][o3] = pack_w(loc4[base + g3], rho4[base + g3], eps4[base + g3]);
    }
    __syncthreads();

#define CHAN(c, x_c, s_c)                                                    \
    {                                                                        \
        const uint4 wv = wp[(c) * Tt + t];                                   \
        const float m0 = bflo(wv.x), m1 = bfhi(wv.x);                        \
        const float m2 = bflo(wv.y), m3 = bfhi(wv.y);                        \
        const float q0 = bflo(wv.z), q1 = bfhi(wv.z);                        \
        const float q2 = bflo(wv.w), q3 = bfhi(wv.w);                        \
        a0 = fmaf(x_c, m0, a0); a1 = fmaf(x_c, m1, a1);                      \
        a2 = fmaf(x_c, m2, a2); a3 = fmaf(x_c, m3, a3);                      \
        const float ya = (x_c) * (s_c);                                      \
        n0 = fmaf(ya, q0, n0); n1 = fmaf(ya, q1, n1);                        \
        n2 = fmaf(ya, q2, n2); n3 = fmaf(ya, q3, n3);                        \
    }

#define CHUNK(t_lo, t_hi)                                                    \
    _Pragma("unroll")                                                        \
    for (int t = (t_lo); t < (t_hi); ++t) {                                  \
        const int kd = t / 9, kh = (t % 9) / 3, kw = t % 3;                  \
        const int off = (kd * Dn + kh) * Dn + kw;                            \
        const float4 xa = x4[v0 + off];                                      \
        const float4 sa = s4[v0 + off];                                      \
        CHAN(0, xa.x, sa.x);                                                 \
        CHAN(1, xa.y, sa.y);                                                 \
        CHAN(2, xa.z, sa.z);                                                 \
        CHAN(3, xa.w, sa.w);                                                 \
    }

#pragma unroll 1
    for (int i = 0; i < n; ++i) {
        const int cur = i & 1;
        const int T = T0 + i;
        const int p = T * PPB + pl;
        const int od = p / (ODn * ODn);
        const int prem = p - od * (ODn * ODn);
        const int oh = prem / ODn;
        const int ow = prem - oh * ODn;
        const size_t v0 = (((size_t)b * Dn + od) * Dn + oh) * Dn + ow;
        const uint4* wp = &wsh[cur][pl * WSTRIDE];
        const bool pf = (i + 1 < n);               // block-uniform
        const size_t nb = (size_t)(T + 1) * UNITS; // next tile base

        float a0=0.f,a1=0.f,a2=0.f,a3=0.f, n0=0.f,n1=0.f,n2=0.f,n3=0.f;

        // Prefetch unit 0 of next tile; pack lands after chunk A.
        float4 PL0, PR0, PE0, PL1, PR1, PE1, PL2, PR2, PE2, PL3, PR3, PE3;
        if (pf) { PL0 = loc4[nb + g0]; PR0 = rho4[nb + g0]; PE0 = eps4[nb + g0]; }

        CHUNK(0, 9)

        if (pf) {
            wsh[cur ^ 1][o0] = pack_w(PL0, PR0, PE0);
            PL1 = loc4[nb + g1]; PR1 = rho4[nb + g1]; PE1 = eps4[nb + g1];
            if (tail) { PL3 = loc4[nb + g3]; PR3 = rho4[nb + g3]; PE3 = eps4[nb + g3]; }
        }

        CHUNK(9, 18)

        if (pf) {
            wsh[cur ^ 1][o1] = pack_w(PL1, PR1, PE1);
            PL2 = loc4[nb + g2]; PR2 = rho4[nb + g2]; PE2 = eps4[nb + g2];
        }

        CHUNK(18, 27)

        if (pf) {
            wsh[cur ^ 1][o2] = pack_w(PL2, PR2, PE2);
            if (tail) wsh[cur ^ 1][o3] = pack_w(PL3, PR3, PE3);
        }

        // ---- Epilogue for tile i: coalesced (8 consecutive p per b) ----
        const size_t ob = (size_t)b * Pn + p;
        const float4 so = ((const float4*)sgn_out)[ob];
        float4 o;
        o.x = fmaf(so.x, n0, a0) + bi.x;
        o.y = fmaf(so.y, n1, a1) + bi.y;
        o.z = fmaf(so.z, n2, a2) + bi.z;
        o.w = fmaf(so.w, n3, a3) + bi.w;
        ((float4*)out)[ob] = o;

        __syncthreads();   // buf[cur] fully read + buf[cur^1] fully written
    }
#undef CHUNK
#undef CHAN
}

extern "C" void kernel_launch(void* const* d_in, const int* in_sizes, int n_in,
                              void* d_out, int out_size, void* d_ws, size_t ws_size,
                              hipStream_t stream) {
    const float* x    = (const float*)d_in[0];
    const float* loc  = (const float*)d_in[1];
    const float* rho  = (const float*)d_in[2];
    const float* bias = (const float*)d_in[3];
    const float* eps  = (const float*)d_in[4];
    const float* si   = (const float*)d_in[5];
    const float* so   = (const float*)d_in[6];
    float* out = (float*)d_out;

    lc3d_flipout_kernel<<<dim3(GRID), dim3(THREADS), 0, stream>>>(
        x, loc, rho, bias, eps, si, so, out);
}

// Round 5
// 223.872 us; speedup vs baseline: 2.3890x; 2.3890x over previous
//
#include <hip/hip_runtime.h>

// LocallyConnected3DFlipout — R12: two-launch split + DMA-pipelined main kernel.
//
//   out[b,p,f] = sum_k patch[b,p,k]*loc[p,k,f]
//              + sign_out[b,p,f]*sum_k (x*sign_in)patch[b,p,k]*(softplus(rho)*eps)[p,k,f]
//              + bias[f]
//
// History: R7/R9/R10 (85-93us) all phase-convoy limited: stage = one ~900cy
// latency-bound HBM round, compute = ~4000cy HBM-idle -> duty 18% -> weight
// stream crawls at 1.27 TB/s (measured == predicted). R5/R11: register
// prefetch across the body ALWAYS spills (R11: VGPR 256, 673MB scratch).
// R8: launch_bounds clamp = spill. Conclusion: overlap must use a mechanism
// with zero VGPR cost -> __builtin_amdgcn_global_load_lds. That requires the
// stage to be a PURE COPY, so:
//   Kernel A: noise = bf16pack(softplus(rho)*eps) -> d_ws, [p][k] linear,
//             fully coalesced stream (95 MB, ~20us). Softplus leaves hot loop.
//   Kernel B: per tile, DMA next tile's loc (f32, [k][p] via per-lane src
//             permute -> conflict-free ds_read_b128 with compile-time imm
//             offsets) + noise (linear, 2-way=free) into LDS double buffer
//             while computing current tile. vmcnt(0)+barrier per tile (T3
//             2-phase recipe). 43KB LDS -> 3 blocks/CU, persistent grid 768,
//             XCD-contiguous Bresenham. Store moved past barrier to overlap.
// loc stays f32 (was bf16) -> mean path more precise; noise rounding identical.
// ws_size guard: fallback to verified R10 kernel (87us) if ws < 18.1 MiB.

constexpr int Bn   = 32;
constexpr int Dn   = 30;
constexpr int Cn   = 4;
constexpr int ODn  = 28;
constexpr int Pn   = ODn * ODn * ODn;   // 21952
constexpr int Tt   = 27;
constexpr int Kn   = Tt * Cn;           // 108
constexpr int PPB  = 8;                 // positions per tile
constexpr int NT   = Pn / PPB;          // 2744 tiles = 8 * 343
constexpr int TPX  = NT / 8;            // 343 tiles per XCD

// --- kernel B geometry ---
constexpr int THREADS_B = 256;          // 8 pos x 32 batches
constexpr int SLOTS  = 96;              // slots per XCD
constexpr int GRID_B = SLOTS * 8;       // 768 = 3 blocks/CU (LDS-bound), all resident
constexpr int LOC_UNITS   = PPB * Kn;          // 864 x 16B (f32x4)  [k][p]
constexpr int NOISE_UNITS = PPB * Kn / 2;      // 432 x 16B (bf16x8) [p][k] linear
constexpr int TILE_UNITS  = LOC_UNITS + NOISE_UNITS;  // 1296
constexpr int NCHUNK = 21;              // ceil(1296/64); chunk20 has 16 valid lanes
constexpr int BUF_UNITS = NCHUNK * 64;  // 1344 (48 pad units, never read)
constexpr int NOISE_BYTES_PER_TILE = PPB * Kn * 8;    // 6912
constexpr int LOC_BYTES_PER_TILE   = PPB * Kn * 16;   // 13824

// --- workspace ---
constexpr size_t WS_NEEDED = (size_t)Pn * Kn * 8;     // 18,966,528 B

__device__ __forceinline__ unsigned bf16rne(float f) {
    unsigned u = __float_as_uint(f);
    return (u + 0x7fffu + ((u >> 16) & 1u)) >> 16;
}
__device__ __forceinline__ float bflo(unsigned u) { return __uint_as_float(u << 16); }
__device__ __forceinline__ float bfhi(unsigned u) { return __uint_as_float(u & 0xffff0000u); }

typedef const __attribute__((address_space(1))) void GASV;
typedef __attribute__((address_space(3))) void LASV;
__device__ __forceinline__ void gld_lds16(const void* g, void* l) {
    __builtin_amdgcn_global_load_lds((GASV*)g, (LASV*)l, 16, 0, 0);
}

// ===================== Kernel A: pack noise weights =====================
// ws[g] (8B) = bf16x4( softplus(rho[g])*eps[g] ), g = p*108 + k. Pure stream.
__global__ __launch_bounds__(256) void pack_noise_kernel(
    const float* __restrict__ rho, const float* __restrict__ eps,
    uint2* __restrict__ ws)
{
    const long NU = (long)Pn * Kn;                    // 2,370,816
    const float4* r4 = (const float4*)rho;
    const float4* e4 = (const float4*)eps;
    for (long g = (long)blockIdx.x * 256 + threadIdx.x; g < NU;
         g += (long)gridDim.x * 256) {
        const float4 R = r4[g];
        const float4 E = e4[g];
        const float nx = (R.x > 15.f ? R.x : __logf(1.f + __expf(R.x))) * E.x;
        const float ny = (R.y > 15.f ? R.y : __logf(1.f + __expf(R.y))) * E.y;
        const float nz = (R.z > 15.f ? R.z : __logf(1.f + __expf(R.z))) * E.z;
        const float nw = (R.w > 15.f ? R.w : __logf(1.f + __expf(R.w))) * E.w;
        uint2 o;
        o.x = bf16rne(nx) | (bf16rne(ny) << 16);
        o.y = bf16rne(nz) | (bf16rne(nw) << 16);
        ws[g] = o;
    }
}

// ===================== Kernel B: DMA-pipelined compute =====================
__global__ __launch_bounds__(THREADS_B) void lc3d_flipout_dma(
    const float* __restrict__ x,        // [B,30,30,30,4]
    const float* __restrict__ loc,      // [P,108,4] f32
    const float* __restrict__ bias,     // [4]
    const uint2* __restrict__ ws,       // [P,108] packed noise bf16x4
    const float* __restrict__ sgn_in,   // [B,30,30,30,4]
    const float* __restrict__ sgn_out,  // [B,P,4]
    float* __restrict__ out)            // [B,P,4]
{
    __shared__ uint4 wsh[2][BUF_UNITS];               // 2 x 21504 B = 43008 B

    const int tid = threadIdx.x;
    const int wv = tid >> 6, ln = tid & 63;

    // ---- XCD-contiguous persistent assignment: 343 tiles over 96 slots ----
    const int xcd  = blockIdx.x & 7;
    const int slot = blockIdx.x >> 3;
    const int tA = (slot * TPX) / SLOTS;
    const int tB = ((slot + 1) * TPX) / SLOTS;
    const int T0 = xcd * TPX + tA;
    const int n  = tB - tA;                           // 3 or 4

    // ---- Per-thread DMA chunk setup (fixed across tiles) ----
    // LDS unit u = chunk*64 + lane. u<864: loc [k][p] (k=u>>3,p=u&7), per-lane
    // global src permute. 864<=u<1296: noise, linear copy from ws. u>=1296: pad.
    const int nch = (wv == 0) ? 6 : 5;
    const int cb  = (wv == 0) ? 0 : (1 + 5 * wv);     // 0,6,11,16
    int  coff[6];
    bool cws[6];
    int  cchk[6];
    #pragma unroll
    for (int j = 0; j < 6; ++j) {
        int ch = (j < nch) ? (cb + j) : cb;
        const int u = ch * 64 + ln;
        if (u < LOC_UNITS) {
            const int k = u >> 3, pp = u & 7;
            coff[j] = pp * (Kn * 16) + k * 16;        // loc src byte offset in tile
            cws[j] = false;
        } else if (u < TILE_UNITS) {
            coff[j] = (u - LOC_UNITS) * 16;           // ws src byte offset in tile
            cws[j] = true;
        } else {
            coff[j] = 0; cws[j] = false;              // pad: harmless re-read
        }
        cchk[j] = ch;
    }

#define ISSUE(TT, BI)                                                        \
    {                                                                        \
        const char* bl = (const char*)loc + (size_t)(TT) * LOC_BYTES_PER_TILE;   \
        const char* bw = (const char*)ws  + (size_t)(TT) * NOISE_BYTES_PER_TILE; \
        char* lb = (char*)&wsh[BI][0];                                       \
        _Pragma("unroll")                                                    \
        for (int j = 0; j < 6; ++j)                                          \
            if (j < nch)                                                     \
                gld_lds16((cws[j] ? bw : bl) + coff[j], lb + cchk[j] * 1024); \
    }

    // ---- Prologue: DMA tile T0 into buffer 0 ----
    ISSUE(T0, 0)
    asm volatile("s_waitcnt vmcnt(0)" ::: "memory");
    __syncthreads();

    const float4* x4 = (const float4*)x;
    const float4* s4 = (const float4*)sgn_in;
    const float4  bi = *(const float4*)bias;
    const int pl = tid & 7;
    const int b  = tid >> 3;                          // 0..31

    float4 o_prev;
    size_t ob_prev = 0;
    bool have_prev = false;

#define CHAN(c, x_c, s_c)                                                    \
    {                                                                        \
        const int kk = (c) * Tt + t;                                         \
        const float4 m = *(const float4*)&lc4[kk * 8 + pl];                  \
        const uint2 nz = nz2[pl * Kn + kk];                                  \
        a0 = fmaf(x_c, m.x, a0); a1 = fmaf(x_c, m.y, a1);                    \
        a2 = fmaf(x_c, m.z, a2); a3 = fmaf(x_c, m.w, a3);                    \
        const float ya = (x_c) * (s_c);                                      \
        n0 = fmaf(ya, bflo(nz.x), n0); n1 = fmaf(ya, bfhi(nz.x), n1);        \
        n2 = fmaf(ya, bflo(nz.y), n2); n3 = fmaf(ya, bfhi(nz.y), n3);        \
    }

#pragma unroll 1
    for (int i = 0; i < n; ++i) {
        const int bufi = i & 1;
        const int T = T0 + i;

        // Issue next tile's DMA first — overlaps this tile's compute.
        if (i + 1 < n) ISSUE(T + 1, bufi ^ 1)

        const int p  = T * PPB + pl;
        const int od = p / (ODn * ODn);
        const int prem = p - od * (ODn * ODn);
        const int oh = prem / ODn;
        const int ow = prem - oh * ODn;
        const size_t v0 = (((size_t)b * Dn + od) * Dn + oh) * Dn + ow;
        const size_t ob = (size_t)b * Pn + p;
        const float4 so = ((const float4*)sgn_out)[ob];   // early issue

        const uint4* lc4 = &wsh[bufi][0];                 // loc [k][p] f32x4
        const uint2* nz2 = (const uint2*)&wsh[bufi][LOC_UNITS]; // noise [p][k]

        float a0=0.f,a1=0.f,a2=0.f,a3=0.f, n0=0.f,n1=0.f,n2=0.f,n3=0.f;

        #pragma unroll
        for (int kd = 0; kd < 3; ++kd) {
            #pragma unroll
            for (int kh = 0; kh < 3; ++kh) {
                const int roff = (kd * Dn + kh) * Dn;
                #pragma unroll
                for (int kw = 0; kw < 3; ++kw) {
                    const int t = (kd * 3 + kh) * 3 + kw;
                    const float4 xa = x4[v0 + roff + kw];
                    const float4 sa = s4[v0 + roff + kw];
                    CHAN(0, xa.x, sa.x);
                    CHAN(1, xa.y, sa.y);
                    CHAN(2, xa.z, sa.z);
                    CHAN(3, xa.w, sa.w);
                }
            }
        }

        float4 o;
        o.x = fmaf(so.x, n0, a0) + bi.x;
        o.y = fmaf(so.y, n1, a1) + bi.y;
        o.z = fmaf(so.z, n2, a2) + bi.z;
        o.w = fmaf(so.w, n3, a3) + bi.w;

        // Wait: next tile's DMA complete (and our VMEM drained), then barrier.
        asm volatile("s_waitcnt vmcnt(0)" ::: "memory");
        __syncthreads();

        // Store AFTER the barrier: overlaps next tile's compute.
        if (have_prev) ((float4*)out)[ob_prev] = o_prev;  // from tile i-1? no:
        // store current now (it's past the barrier already):
        ((float4*)out)[ob] = o;
        have_prev = false;
        (void)o_prev; (void)ob_prev;
    }
#undef CHAN
#undef ISSUE
}

// ===================== Fallback: verified R10 kernel (87us) =====================
constexpr int PPB_F = 16;
constexpr int NT_F  = Pn / PPB_F;       // 1372
constexpr int WSTRIDE_F = Kn + 1;       // 109

__device__ __forceinline__ uint4 pack_w(const float4 L, const float4 R, const float4 E) {
    float nx = (R.x > 15.f ? R.x : __logf(1.f + __expf(R.x))) * E.x;
    float ny = (R.y > 15.f ? R.y : __logf(1.f + __expf(R.y))) * E.y;
    float nz = (R.z > 15.f ? R.z : __logf(1.f + __expf(R.z))) * E.z;
    float nw = (R.w > 15.f ? R.w : __logf(1.f + __expf(R.w))) * E.w;
    uint4 pk;
    pk.x = bf16rne(L.x) | (bf16rne(L.y) << 16);
    pk.y = bf16rne(L.z) | (bf16rne(L.w) << 16);
    pk.z = bf16rne(nx)  | (bf16rne(ny) << 16);
    pk.w = bf16rne(nz)  | (bf16rne(nw) << 16);
    return pk;
}

__global__ __launch_bounds__(512) void lc3d_fallback(
    const float* __restrict__ x, const float* __restrict__ loc,
    const float* __restrict__ rho, const float* __restrict__ bias,
    const float* __restrict__ eps, const float* __restrict__ sgn_in,
    const float* __restrict__ sgn_out, float* __restrict__ out)
{
    __shared__ uint4 wsh[PPB_F * WSTRIDE_F];
    const int tid = threadIdx.x;
    const int xcd  = blockIdx.x & 7;
    const int slot = blockIdx.x >> 3;
    const int Tx = (xcd < 4) ? xcd * 172 : 688 + (xcd - 4) * 171;
    const int p_base = (Tx + slot) * PPB_F;
    {
        const float4* loc4 = (const float4*)loc + (size_t)p_base * Kn;
        const float4* rho4 = (const float4*)rho + (size_t)p_base * Kn;
        const float4* eps4 = (const float4*)eps + (size_t)p_base * Kn;
        const int g0 = tid, g1 = tid + 512, g2 = tid + 1024;
        const float4 L0 = loc4[g0], R0 = rho4[g0], E0 = eps4[g0];
        const float4 L1 = loc4[g1], R1 = rho4[g1], E1 = eps4[g1];
        const float4 L2 = loc4[g2], R2 = rho4[g2], E2 = eps4[g2];
        { const int plc = g0 / Kn, k = g0 - plc * Kn; wsh[plc * WSTRIDE_F + k] = pack_w(L0, R0, E0); }
        { const int plc = g1 / Kn, k = g1 - plc * Kn; wsh[plc * WSTRIDE_F + k] = pack_w(L1, R1, E1); }
        { const int plc = g2 / Kn, k = g2 - plc * Kn; wsh[plc * WSTRIDE_F + k] = pack_w(L2, R2, E2); }
        if (tid < PPB_F * Kn - 1536) {
            const int g3 = tid + 1536;
            const int plc = g3 / Kn, k = g3 - plc * Kn;
            wsh[plc * WSTRIDE_F + k] = pack_w(loc4[g3], rho4[g3], eps4[g3]);
        }
    }
    __syncthreads();
    const int pl = tid & 15;
    const int b  = tid >> 4;
    const int p  = p_base + pl;
    const int od = p / (ODn * ODn);
    const int prem = p - od * (ODn * ODn);
    const int oh = prem / ODn;
    const int ow = prem - oh * ODn;
    const float4* x4 = (const float4*)x;
    const float4* s4 = (const float4*)sgn_in;
    const size_t v0 = (((size_t)b * Dn + od) * Dn + oh) * Dn + ow;
    const uint4* wp = wsh + pl * WSTRIDE_F;
    float a0=0.f,a1=0.f,a2=0.f,a3=0.f, n0=0.f,n1=0.f,n2=0.f,n3=0.f;
#define CHANF(c, x_c, s_c)                                                   \
    {                                                                        \
        const uint4 wvv = wp[(c) * Tt + t];                                  \
        a0 = fmaf(x_c, bflo(wvv.x), a0); a1 = fmaf(x_c, bfhi(wvv.x), a1);    \
        a2 = fmaf(x_c, bflo(wvv.y), a2); a3 = fmaf(x_c, bfhi(wvv.y), a3);    \
        const float ya = (x_c) * (s_c);                                      \
        n0 = fmaf(ya, bflo(wvv.z), n0); n1 = fmaf(ya, bfhi(wvv.z), n1);      \
        n2 = fmaf(ya, bflo(wvv.w), n2); n3 = fmaf(ya, bfhi(wvv.w), n3);      \
    }
    #pragma unroll
    for (int kd = 0; kd < 3; ++kd)
        #pragma unroll
        for (int kh = 0; kh < 3; ++kh) {
            const int roff = (kd * Dn + kh) * Dn;
            #pragma unroll
            for (int kw = 0; kw < 3; ++kw) {
                const int t = (kd * 3 + kh) * 3 + kw;
                const float4 xa = x4[v0 + roff + kw];
                const float4 sa = s4[v0 + roff + kw];
                CHANF(0, xa.x, sa.x); CHANF(1, xa.y, sa.y);
                CHANF(2, xa.z, sa.z); CHANF(3, xa.w, sa.w);
            }
        }
#undef CHANF
    const float4 bi = *(const float4*)bias;
    const size_t ob = (size_t)b * Pn + p;
    const float4 so = ((const float4*)sgn_out)[ob];
    float4 o;
    o.x = fmaf(so.x, n0, a0) + bi.x;
    o.y = fmaf(so.y, n1, a1) + bi.y;
    o.z = fmaf(so.z, n2, a2) + bi.z;
    o.w = fmaf(so.w, n3, a3) + bi.w;
    ((float4*)out)[ob] = o;
}

extern "C" void kernel_launch(void* const* d_in, const int* in_sizes, int n_in,
                              void* d_out, int out_size, void* d_ws, size_t ws_size,
                              hipStream_t stream) {
    const float* x    = (const float*)d_in[0];
    const float* loc  = (const float*)d_in[1];
    const float* rho  = (const float*)d_in[2];
    const float* bias = (const float*)d_in[3];
    const float* eps  = (const float*)d_in[4];
    const float* si   = (const float*)d_in[5];
    const float* so   = (const float*)d_in[6];
    float* out = (float*)d_out;

    if (d_ws != nullptr && ws_size >= WS_NEEDED) {
        pack_noise_kernel<<<dim3(2048), dim3(256), 0, stream>>>(
            rho, eps, (uint2*)d_ws);
        lc3d_flipout_dma<<<dim3(GRID_B), dim3(THREADS_B), 0, stream>>>(
            x, loc, bias, (const uint2*)d_ws, si, so, out);
    } else {
        lc3d_fallback<<<dim3(NT_F), dim3(512), 0, stream>>>(
            x, loc, rho, bias, eps, si, so, out);
    }
}